// Round 9
// baseline (27.811 us; speedup 1.0000x reference)
//
#include <hip/hip_runtime.h>
#include <hip/hip_fp16.h>
#include <math.h>

#define FEAT 64

typedef float fx4 __attribute__((ext_vector_type(4)));

// ---- pass A: node_value f32 -> SLICE-MAJOR fp16 table ----
// Layout: table[slice][node][32 features], slice in {0,1}.
// Entry (node,slice) = 64B contiguous -> one cache line per edge-slice gather.
__global__ __launch_bounds__(256) void convert_f32_to_f16_sliced_kernel(
    const float4* __restrict__ src4,   // node_value as float4; i -> (node, 4 feats)
    uint2* __restrict__ dst,           // fp16 table as uint2 (4 halves)
    int n4, int n_nodes)
{
    const int i = blockIdx.x * blockDim.x + threadIdx.x;
    if (i >= n4) return;
    const int node = i >> 4;           // 16 float4 per node row
    const int f0   = (i & 15) * 4;     // first feature of this float4
    const float4 v = src4[i];
    const __half2 h0 = __floats2half2_rn(v.x, v.y);
    const __half2 h1 = __floats2half2_rn(v.z, v.w);
    uint2 o;
    o.x = *reinterpret_cast<const unsigned int*>(&h0);
    o.y = *reinterpret_cast<const unsigned int*>(&h1);
    const int s  = f0 >> 5;            // slice
    const int fo = f0 & 31;            // feature offset within slice
    // uint2 units: slice stride = n_nodes*8, node stride = 8, feat pair = fo/4
    dst[(size_t)s * n_nodes * 8 + (size_t)node * 8 + (fo >> 2)] = o;
}

// ---- pass B: softmax + weighted gather-aggregate ----
// 4 lanes per (node, slice); slice = blockIdx & 1 so each XCD (round-robin
// blockIdx -> XCD) touches only ONE 3.2MB table slice -> L2-resident.
// Lane owns 8 features (16B uint4); 4 lanes cover the 64B slice entry ->
// one coalesced 64B transaction per edge-slice gather.
__global__ __launch_bounds__(256) void gat_softmax_agg_kernel(
    const int* __restrict__ row_ptr,
    const int* __restrict__ col_idx,
    const float* __restrict__ edge_scores,
    const uint4* __restrict__ nv16,    // sliced table, 4 uint4 per (node,slice)
    float* __restrict__ out,           // f32 out, FEAT floats per node
    int n_nodes)
{
    const int slice = blockIdx.x & 1;
    const int nb    = blockIdx.x >> 1;          // node-block
    const int g     = threadIdx.x >> 2;         // group (node) within block
    const int lane  = threadIdx.x & 3;          // lane within group
    const int node  = nb * 64 + g;
    if (node >= n_nodes) return;

    const int start = row_ptr[node];
    const int end   = row_ptr[node + 1];
    const int deg   = end - start;

    // this XCD's table slice; entry for node c = 4 uint4 at tab[c*4 .. c*4+3]
    const uint4* tab = nv16 + (size_t)slice * n_nodes * 4;

    fx4 accA = (fx4)0.f;   // features slice*32 + lane*8 + 0..3
    fx4 accB = (fx4)0.f;   // features slice*32 + lane*8 + 4..7

    if (deg == 16 && (start & 3) == 0) {
        // 16 scores into registers (group-uniform addresses -> broadcast)
        float s[16];
        {
            const fx4* s4 = (const fx4*)(edge_scores + start);
            #pragma unroll
            for (int i = 0; i < 4; ++i) {
                const fx4 sv = s4[i];
                s[4*i+0] = sv.x; s[4*i+1] = sv.y; s[4*i+2] = sv.z; s[4*i+3] = sv.w;
            }
        }

        // in-register softmax; exp computed once, stored back into s[]
        float m = s[0];
        #pragma unroll
        for (int k = 1; k < 16; ++k) m = fmaxf(m, s[k]);
        float ssum = 0.f;
        #pragma unroll
        for (int k = 0; k < 16; ++k) { s[k] = __expf(s[k] - m); ssum += s[k]; }
        const float inv = 1.0f / ssum;

        // issue all 16 gathers; group's 4 lanes cover one 64B line per edge
        uint4 r[16];
        {
            const int4* c4 = (const int4*)(col_idx + start);
            #pragma unroll
            for (int i = 0; i < 4; ++i) {
                const int4 cv = c4[i];
                r[4*i+0] = tab[(unsigned)cv.x * 4u + lane];
                r[4*i+1] = tab[(unsigned)cv.y * 4u + lane];
                r[4*i+2] = tab[(unsigned)cv.z * 4u + lane];
                r[4*i+3] = tab[(unsigned)cv.w * 4u + lane];
            }
        }

        // consume: fp16 -> f32 FMA, weight = s[k]*inv
        #pragma unroll
        for (int k = 0; k < 16; ++k) {
            const float w = s[k] * inv;
            const __half2 h0 = *reinterpret_cast<const __half2*>(&r[k].x);
            const __half2 h1 = *reinterpret_cast<const __half2*>(&r[k].y);
            const __half2 h2 = *reinterpret_cast<const __half2*>(&r[k].z);
            const __half2 h3 = *reinterpret_cast<const __half2*>(&r[k].w);
            const float2 f0 = __half22float2(h0);
            const float2 f1 = __half22float2(h1);
            const float2 f2 = __half22float2(h2);
            const float2 f3 = __half22float2(h3);
            accA.x = fmaf(w, f0.x, accA.x);
            accA.y = fmaf(w, f0.y, accA.y);
            accA.z = fmaf(w, f1.x, accA.z);
            accA.w = fmaf(w, f1.y, accA.w);
            accB.x = fmaf(w, f2.x, accB.x);
            accB.y = fmaf(w, f2.y, accB.y);
            accB.z = fmaf(w, f3.x, accB.z);
            accB.w = fmaf(w, f3.y, accB.w);
        }
    } else if (deg > 0) {
        // general-degree fallback: serial, scalar, still pure
        float m = -INFINITY;
        for (int e = start; e < end; ++e) m = fmaxf(m, edge_scores[e]);
        float ssum = 0.f;
        for (int e = start; e < end; ++e) ssum += __expf(edge_scores[e] - m);
        const float inv = 1.0f / ssum;
        for (int e = start; e < end; ++e) {
            const float w = __expf(edge_scores[e] - m) * inv;
            const uint4 raw = tab[(unsigned)col_idx[e] * 4u + lane];
            const __half2 h0 = *reinterpret_cast<const __half2*>(&raw.x);
            const __half2 h1 = *reinterpret_cast<const __half2*>(&raw.y);
            const __half2 h2 = *reinterpret_cast<const __half2*>(&raw.z);
            const __half2 h3 = *reinterpret_cast<const __half2*>(&raw.w);
            const float2 f0 = __half22float2(h0);
            const float2 f1 = __half22float2(h1);
            const float2 f2 = __half22float2(h2);
            const float2 f3 = __half22float2(h3);
            accA.x = fmaf(w, f0.x, accA.x);
            accA.y = fmaf(w, f0.y, accA.y);
            accA.z = fmaf(w, f1.x, accA.z);
            accA.w = fmaf(w, f1.y, accA.w);
            accB.x = fmaf(w, f2.x, accB.x);
            accB.y = fmaf(w, f2.y, accB.y);
            accB.z = fmaf(w, f3.x, accB.z);
            accB.w = fmaf(w, f3.y, accB.w);
        }
    }

    // lane writes 32B; 4 lanes cover the slice's contiguous 128B f32 span
    fx4* o4 = (fx4*)(out + (size_t)node * FEAT + slice * 32 + lane * 8);
    o4[0] = accA;
    o4[1] = accB;
}

extern "C" void kernel_launch(void* const* d_in, const int* in_sizes, int n_in,
                              void* d_out, int out_size, void* d_ws, size_t ws_size,
                              hipStream_t stream) {
    const int*    row_ptr     = (const int*)d_in[0];
    const int*    col_idx     = (const int*)d_in[1];
    const float*  edge_scores = (const float*)d_in[2];
    const float*  node_value  = (const float*)d_in[3];
    float*        out         = (float*)d_out;

    const int n_nodes = in_sizes[0] - 1;
    const int n_feat_total = in_sizes[3];          // n_nodes * FEAT floats

    uint4* nv16 = (uint4*)d_ws;                    // 6.4 MB sliced table

    // pass A: convert node_value to slice-major fp16
    {
        const int n4 = n_feat_total / 4;
        const int block = 256;
        const int grid = (n4 + block - 1) / block;
        convert_f32_to_f16_sliced_kernel<<<grid, block, 0, stream>>>(
            (const float4*)node_value, (uint2*)nv16, n4, n_nodes);
    }

    // pass B: softmax + aggregate; blockIdx parity = feature slice
    {
        const int block = 256;                     // 64 nodes per block-slice
        const int nblocks_nodes = (n_nodes + 63) / 64;
        const int grid = 2 * nblocks_nodes;
        gat_softmax_agg_kernel<<<grid, block, 0, stream>>>(
            row_ptr, col_idx, edge_scores, nv16, out, n_nodes);
    }
}

// Round 10
// 26.009 us; speedup vs baseline: 1.0693x; 1.0693x over previous
//
#include <hip/hip_runtime.h>
#include <hip/hip_fp16.h>
#include <math.h>

#define FEAT 64

typedef float fx4 __attribute__((ext_vector_type(4)));

// ---- pass A: node_value f32 -> f16 table in workspace (streaming) ----
__global__ __launch_bounds__(256) void convert_f32_to_f16_kernel(
    const float4* __restrict__ src4,
    uint2* __restrict__ dst2,
    int n4)
{
    const int i = blockIdx.x * blockDim.x + threadIdx.x;
    if (i >= n4) return;
    const float4 v = src4[i];
    const __half2 h0 = __floats2half2_rn(v.x, v.y);
    const __half2 h1 = __floats2half2_rn(v.z, v.w);
    uint2 o;
    o.x = *reinterpret_cast<const unsigned int*>(&h0);
    o.y = *reinterpret_cast<const unsigned int*>(&h1);
    dst2[i] = o;
}

// ---- pass B: softmax + weighted gather-aggregate (8 lanes per node) ----
// Lane `sub` owns features [8*sub, 8*sub+8). 16B uint4 gathers; 8 lanes x
// 16B = 128B contiguous per edge row (one line request). Gathers are issued
// BEFORE the softmax VALU work so exp/reduce overlaps gather latency.
__global__ __launch_bounds__(256) void gat_softmax_agg_kernel(
    const int* __restrict__ row_ptr,
    const int* __restrict__ col_idx,
    const float* __restrict__ edge_scores,
    const uint4* __restrict__ nv16,    // fp16 table, 8 uint4 per node row
    float4* __restrict__ out4,         // f32 out, 16 float4 per node row
    int n_nodes)
{
    const int tid  = blockIdx.x * blockDim.x + threadIdx.x;
    const int node = tid >> 3;
    const int sub  = threadIdx.x & 7;
    if (node >= n_nodes) return;

    const int start = row_ptr[node];
    const int end   = row_ptr[node + 1];
    const int deg   = end - start;

    float4 accA = make_float4(0.f, 0.f, 0.f, 0.f);   // features 8*sub+0..3
    float4 accB = make_float4(0.f, 0.f, 0.f, 0.f);   // features 8*sub+4..7

    if (deg == 16 && (start & 3) == 0) {
        // issue col loads + all 16 gathers FIRST (addresses independent of
        // softmax); the exp/reduce below overlaps the in-flight gathers
        uint4 r[16];
        {
            const int4* c4 = (const int4*)(col_idx + start);
            #pragma unroll
            for (int i = 0; i < 4; ++i) {
                const int4 cv = c4[i];
                r[4*i+0] = nv16[(unsigned)cv.x * 8u + sub];
                r[4*i+1] = nv16[(unsigned)cv.y * 8u + sub];
                r[4*i+2] = nv16[(unsigned)cv.z * 8u + sub];
                r[4*i+3] = nv16[(unsigned)cv.w * 8u + sub];
            }
        }

        // 16 scores into registers (group-uniform addresses -> broadcast)
        float s[16];
        {
            const fx4* s4 = (const fx4*)(edge_scores + start);
            #pragma unroll
            for (int i = 0; i < 4; ++i) {
                const fx4 sv = s4[i];
                s[4*i+0] = sv.x; s[4*i+1] = sv.y; s[4*i+2] = sv.z; s[4*i+3] = sv.w;
            }
        }

        // in-register softmax; exp computed once, stored back into s[]
        float m = s[0];
        #pragma unroll
        for (int k = 1; k < 16; ++k) m = fmaxf(m, s[k]);
        float ssum = 0.f;
        #pragma unroll
        for (int k = 0; k < 16; ++k) { s[k] = __expf(s[k] - m); ssum += s[k]; }
        const float inv = 1.0f / ssum;

        // consume: fp16 -> f32 FMA, weight = s[k]*inv
        #pragma unroll
        for (int k = 0; k < 16; ++k) {
            const float w = s[k] * inv;
            const __half2 h0 = *reinterpret_cast<const __half2*>(&r[k].x);
            const __half2 h1 = *reinterpret_cast<const __half2*>(&r[k].y);
            const __half2 h2 = *reinterpret_cast<const __half2*>(&r[k].z);
            const __half2 h3 = *reinterpret_cast<const __half2*>(&r[k].w);
            const float2 f0 = __half22float2(h0);
            const float2 f1 = __half22float2(h1);
            const float2 f2 = __half22float2(h2);
            const float2 f3 = __half22float2(h3);
            accA.x = fmaf(w, f0.x, accA.x);
            accA.y = fmaf(w, f0.y, accA.y);
            accA.z = fmaf(w, f1.x, accA.z);
            accA.w = fmaf(w, f1.y, accA.w);
            accB.x = fmaf(w, f2.x, accB.x);
            accB.y = fmaf(w, f2.y, accB.y);
            accB.z = fmaf(w, f3.x, accB.z);
            accB.w = fmaf(w, f3.y, accB.w);
        }
    } else if (deg > 0) {
        // general-degree fallback: serial, scalar, still pure
        float m = -INFINITY;
        for (int e = start; e < end; ++e) m = fmaxf(m, edge_scores[e]);
        float ssum = 0.f;
        for (int e = start; e < end; ++e) ssum += __expf(edge_scores[e] - m);
        const float inv = 1.0f / ssum;
        for (int e = start; e < end; ++e) {
            const float w = __expf(edge_scores[e] - m) * inv;
            const uint4 raw = nv16[(unsigned)col_idx[e] * 8u + sub];
            const __half2 h0 = *reinterpret_cast<const __half2*>(&raw.x);
            const __half2 h1 = *reinterpret_cast<const __half2*>(&raw.y);
            const __half2 h2 = *reinterpret_cast<const __half2*>(&raw.z);
            const __half2 h3 = *reinterpret_cast<const __half2*>(&raw.w);
            const float2 f0 = __half22float2(h0);
            const float2 f1 = __half22float2(h1);
            const float2 f2 = __half22float2(h2);
            const float2 f3 = __half22float2(h3);
            accA.x = fmaf(w, f0.x, accA.x);
            accA.y = fmaf(w, f0.y, accA.y);
            accA.z = fmaf(w, f1.x, accA.z);
            accA.w = fmaf(w, f1.y, accA.w);
            accB.x = fmaf(w, f2.x, accB.x);
            accB.y = fmaf(w, f2.y, accB.y);
            accB.z = fmaf(w, f3.x, accB.z);
            accB.w = fmaf(w, f3.y, accB.w);
        }
    }

    // lane sub owns float4 slots 2*sub and 2*sub+1 of the 16-float4 row
    out4[(long)node * (FEAT/4) + 2*sub + 0] = accA;
    out4[(long)node * (FEAT/4) + 2*sub + 1] = accB;
}

extern "C" void kernel_launch(void* const* d_in, const int* in_sizes, int n_in,
                              void* d_out, int out_size, void* d_ws, size_t ws_size,
                              hipStream_t stream) {
    const int*    row_ptr     = (const int*)d_in[0];
    const int*    col_idx     = (const int*)d_in[1];
    const float*  edge_scores = (const float*)d_in[2];
    const float*  node_value  = (const float*)d_in[3];
    float4*       out4        = (float4*)d_out;

    const int n_nodes = in_sizes[0] - 1;
    const int n_feat_total = in_sizes[3];          // n_nodes * FEAT floats

    uint4* nv16 = (uint4*)d_ws;                    // 6.4 MB in workspace

    // pass A: convert node_value to fp16
    {
        const int n4 = n_feat_total / 4;
        const int block = 256;
        const int grid = (n4 + block - 1) / block;
        convert_f32_to_f16_kernel<<<grid, block, 0, stream>>>(
            (const float4*)node_value, (uint2*)nv16, n4);
    }

    // pass B: softmax + aggregate (8 threads per node)
    {
        const int block = 256;                     // 32 nodes per block
        const long threads_total = (long)n_nodes * 8;
        const int grid = (int)((threads_total + block - 1) / block);
        gat_softmax_agg_kernel<<<grid, block, 0, stream>>>(
            row_ptr, col_idx, edge_scores, nv16, out4, n_nodes);
    }
}